// Round 10
// baseline (312.178 us; speedup 1.0000x reference)
//
#include <hip/hip_runtime.h>
#include <hip/hip_bf16.h>
#include <math.h>

// Problem constants (B,T,E)=(4,2048,512), H=8, D=64, HID=H*E=4096.
#define Bsz 4
#define Tt 2048
#define Ee 512
#define Hh 8
#define Dd 64
#define HIDs 4096
#define Mrows (Bsz * Tt)   // 8192 token rows

typedef __attribute__((ext_vector_type(8))) short short8;    // 8 bf16 (4 VGPRs)
typedef __attribute__((ext_vector_type(4))) float f32x4;     // 16x16 MFMA acc
typedef __attribute__((ext_vector_type(16))) float f32x16;   // 32x32 MFMA acc

#define AS1 __attribute__((address_space(1)))
#define AS3 __attribute__((address_space(3)))

__device__ __forceinline__ unsigned short f2bfu(float f) {   // RNE float->bf16 bits
    unsigned u = __float_as_uint(f);
    return (unsigned short)((u + 0x7fffu + ((u >> 16) & 1u)) >> 16);
}
__device__ __forceinline__ unsigned short truncbf(float f) { // truncating (P only)
    return (unsigned short)(__float_as_uint(f) >> 16);
}

// Swizzled ds_read for 64B-row LDS tiles ([row][4 x 16B slots], phys slot =
// logical slot ^ ((row>>1)&3): rows 0-7 cover all 8 (parity,slot) bank
// groups -> 2-way residual = free). Staging inverse-permutes the GLOBAL
// source k-offset (global_load_lds dest stays linear, rule #21).
__device__ __forceinline__ short8 ld_sw(const __hip_bfloat16* base, int R, int sl) {
    return *(const short8*)(base + R * 32 + (((sl) ^ ((R >> 1) & 3)) << 3));
}

// ---------------------------------------------------------------------------
// LN body (shared by startup + LN2 kernels).
__device__ __forceinline__ void ln_body(const float* __restrict__ x,
        const float* __restrict__ g, const float* __restrict__ b,
        const float* __restrict__ addb,
        float* __restrict__ out_f, __hip_bfloat16* __restrict__ out_bf,
        int row) {
    int tid = threadIdx.x;
    const float* xr = x + (size_t)row * Ee;
    float v0 = xr[tid];
    float v1 = xr[tid + 256];
    float s = v0 + v1;
    float sq = v0 * v0 + v1 * v1;
#pragma unroll
    for (int off = 32; off > 0; off >>= 1) {
        s  += __shfl_xor(s, off, 64);
        sq += __shfl_xor(sq, off, 64);
    }
    __shared__ float ls[4], lq[4];
    int wid = tid >> 6, lane = tid & 63;
    if (lane == 0) { ls[wid] = s; lq[wid] = sq; }
    __syncthreads();
    s  = ls[0] + ls[1] + ls[2] + ls[3];
    sq = lq[0] + lq[1] + lq[2] + lq[3];
    float mean = s * (1.0f / Ee);
    float var  = sq * (1.0f / Ee) - mean * mean;   // biased var, like jnp.var
    float rstd = rsqrtf(var + 1e-5f);
    float o0 = (v0 - mean) * rstd * g[tid]       + b[tid];
    float o1 = (v1 - mean) * rstd * g[tid + 256] + b[tid + 256];
    float* orow = out_f + (size_t)row * Ee;
    orow[tid]       = o0 + addb[tid];
    orow[tid + 256] = o1 + addb[tid + 256];
    __hip_bfloat16* brow = out_bf + (size_t)row * Ee;
    brow[tid]       = __float2bfloat16(o0);
    brow[tid + 256] = __float2bfloat16(o1);
}

__global__ __launch_bounds__(256) void ln_kernel(const float* __restrict__ x,
        const float* __restrict__ g, const float* __restrict__ b,
        const float* __restrict__ addb,
        float* __restrict__ out_f, __hip_bfloat16* __restrict__ out_bf) {
    ln_body(x, g, b, addb, out_f, out_bf, blockIdx.x);
}

// ---------------------------------------------------------------------------
// Startup: LN1 (blocks [0,8192)) + all weight repacks ([8192,9472)) fused.
__device__ __forceinline__ void tr_tile(const float* __restrict__ in,
        __hip_bfloat16* __restrict__ outp, int R, int C, int c0, int r0) {
    __shared__ float tile[64][65];
    int tc = threadIdx.x & 63, tg = threadIdx.x >> 6;
#pragma unroll
    for (int i = 0; i < 16; ++i) {
        int r = tg * 16 + i;
        tile[r][tc] = in[(size_t)(r0 + r) * C + c0 + tc];
    }
    __syncthreads();
#pragma unroll
    for (int i = 0; i < 16; ++i) {
        int cc = tg * 16 + i;
        outp[(size_t)(c0 + cc) * R + r0 + tc] = __float2bfloat16(tile[tc][cc]);
    }
}
__global__ __launch_bounds__(256) void startup_kernel(
        const float* __restrict__ x, const float* __restrict__ g1,
        const float* __restrict__ be1, const float* __restrict__ bo,
        float* __restrict__ xn, __hip_bfloat16* __restrict__ xn_bf,
        const float* __restrict__ Wq, const float* __restrict__ Wk,
        const float* __restrict__ Wv, const float* __restrict__ Wo,
        const float* __restrict__ W1, const float* __restrict__ W2,
        __hip_bfloat16* __restrict__ bqT, __hip_bfloat16* __restrict__ woT,
        __hip_bfloat16* __restrict__ w1T, __hip_bfloat16* __restrict__ w2T) {
    if (blockIdx.x < Mrows) {
        ln_body(x, g1, be1, bo, xn, xn_bf, blockIdx.x);
        return;
    }
    int blk = blockIdx.x - Mrows;
    if (blk < 192) {                 // qkv: p*64 + h*8 + et
        int p = blk >> 6, h = (blk >> 3) & 7, et = blk & 7;
        const float* W = (p == 0) ? Wq : ((p == 1) ? Wk : Wv);
        float sc = (p == 0) ? 0.022097086912079608f * 1.4426950408889634f : 1.0f;
        __shared__ float tile[64][65];
        int td = threadIdx.x & 63, tg = threadIdx.x >> 6;
#pragma unroll
        for (int i = 0; i < 16; ++i) {
            int e = tg * 16 + i;
            tile[e][td] = W[((size_t)h * Ee + et * 64 + e) * Dd + td] * sc;
        }
        __syncthreads();
#pragma unroll
        for (int i = 0; i < 16; ++i) {
            int d = tg * 16 + i;
            bqT[((size_t)(p * 512 + h * 64 + d)) * Ee + et * 64 + td] =
                __float2bfloat16(tile[td][d]);
        }
    } else if (blk < 256) {
        int t = blk - 192;           // 8x8
        tr_tile(Wo, woT, 512, 512, (t & 7) * 64, (t >> 3) * 64);
    } else if (blk < 768) {
        int t = blk - 256;           // 64x8
        tr_tile(W1, w1T, 512, HIDs, (t & 63) * 64, (t >> 6) * 64);
    } else {
        int t = blk - 768;           // 8x64
        tr_tile(W2, w2T, HIDs, 512, (t & 7) * 64, (t >> 3) * 64);
    }
}

// ---------------------------------------------------------------------------
// bf16 MFMA GEMM (QKV): 128x128 tile, BK=64, 2-buffer depth-1 prefetch with
// counted vmcnt(8) (tile t+1 staged before compute of t; never drain to 0
// in-loop) + bank-conflict swizzle. XCD swizzle. Epilogue: per-wave LDS
// transpose -> uint4 coalesced bf16 stores.
__global__ __launch_bounds__(256) void mfma_gemm(
        const __hip_bfloat16* __restrict__ A, int lda,
        const __hip_bfloat16* __restrict__ B, int ldb,
        __hip_bfloat16* __restrict__ Cb, int ldc, int K, int nx) {
    __shared__ __hip_bfloat16 S[32768];   // 2 bufs x (A 16KB | B 16KB) = 64KB
    int tid = threadIdx.x;
    int lane = tid & 63, wave = tid >> 6;
    int wm = wave >> 1, wn = wave & 1;
    int L = blockIdx.x;
    int slots = (int)gridDim.x >> 3;
    int v = (L & 7) * slots + (L >> 3);
    int bx = v % nx, by = v / nx;
    int row0 = by * 128, col0 = bx * 128;
    f32x4 acc[4][4];
#pragma unroll
    for (int i = 0; i < 4; ++i)
#pragma unroll
        for (int j = 0; j < 4; ++j) acc[i][j] = (f32x4){0.f, 0.f, 0.f, 0.f};

    int fr = lane & 15, sl = lane >> 4;
    int T = K >> 6;

// Stage tile tt (A 128x64 + B 128x64) into buffer bb. Dest linear; source
// k-offset inverse-swizzled to match ld_sw.
#define STAGEQ(tt, bb)                                                        \
    do {                                                                      \
        int kk_ = (tt) * 64;                                                  \
        _Pragma("unroll")                                                     \
        for (int j = 0; j < 4; ++j) {                                         \
            int c = j * 256 + tid;                                            \
            int p = c >> 9, cp = c & 511;                                     \
            int r = cp >> 2, s = cp & 3;                                      \
            int kg = ((s ^ ((r >> 1) & 3)) << 3);                             \
            int cb = j * 256 + wave * 64;                                     \
            int ko = kk_ + p * 32 + kg;                                       \
            __builtin_amdgcn_global_load_lds(                                 \
                (const AS1 void*)(A + (size_t)(row0 + r) * lda + ko),         \
                (AS3 void*)(S + (bb) * 16384 + cb * 8), 16, 0, 0);            \
            __builtin_amdgcn_global_load_lds(                                 \
                (const AS1 void*)(B + (size_t)(col0 + r) * ldb + ko),         \
                (AS3 void*)(S + (bb) * 16384 + 8192 + cb * 8), 16, 0, 0);     \
        }                                                                     \
    } while (0)

    STAGEQ(0, 0);
    for (int t = 0; t < T; ++t) {
        int tn = (t + 1 < T) ? t + 1 : 0;   // wrap keeps vmcnt uniform
        STAGEQ(tn, (t + 1) & 1);
        asm volatile("s_waitcnt vmcnt(8)" ::: "memory");  // tile t's loads done
        __builtin_amdgcn_s_barrier();
        asm volatile("" ::: "memory");
        const __hip_bfloat16* Ab = S + (t & 1) * 16384;
        const __hip_bfloat16* Bb = Ab + 8192;
#pragma unroll
        for (int ks = 0; ks < 2; ++ks) {
            short8 afr[4], bfr[4];
#pragma unroll
            for (int i = 0; i < 4; ++i) {
                afr[i] = ld_sw(Ab + ks * 4096, wm * 64 + i * 16 + fr, sl);
                bfr[i] = ld_sw(Bb + ks * 4096, wn * 64 + i * 16 + fr, sl);
            }
#pragma unroll
            for (int i = 0; i < 4; ++i)
#pragma unroll
                for (int j = 0; j < 4; ++j)
                    acc[i][j] = __builtin_amdgcn_mfma_f32_16x16x32_bf16(afr[i], bfr[j], acc[i][j], 0, 0, 0);
        }
        asm volatile("" ::: "memory");
        __builtin_amdgcn_s_barrier();   // readers done before next overwrite
        asm volatile("" ::: "memory");
    }
#undef STAGEQ
    // ---- epilogue: drain dangling wrap-prefetch DMA, then reuse LDS
    asm volatile("s_waitcnt vmcnt(0)" ::: "memory");
    __syncthreads();
    unsigned short* Ew = (unsigned short*)S + wave * 1152;   // 16 x 72
    const __hip_bfloat16* Er = (const __hip_bfloat16*)Ew;
    int rq = (lane >> 4) << 2;
    int rr = lane >> 2, cb2 = (lane & 3) * 16;
#pragma unroll
    for (int i = 0; i < 4; ++i) {
#pragma unroll
        for (int j = 0; j < 4; ++j)
#pragma unroll
            for (int gi = 0; gi < 4; ++gi)
                Ew[(rq + gi) * 72 + j * 16 + fr] = f2bfu(acc[i][j][gi]);
        uint4 v0 = *(const uint4*)(Er + rr * 72 + cb2);
        uint4 v1 = *(const uint4*)(Er + rr * 72 + cb2 + 8);
        size_t rg = (size_t)(row0 + wm * 64 + i * 16 + rr) * ldc + col0 + wn * 64 + cb2;
        *(uint4*)(Cb + rg)     = v0;
        *(uint4*)(Cb + rg + 8) = v1;
    }
}

// ---------------------------------------------------------------------------
// bf16 MFMA GEMM, 128x64 tile, full K. 4 waves x (32m x 64n). 3-buffer
// depth-2 prefetch with counted vmcnt(12) + bank-conflict swizzle.
// Epilogue: Cf[ci] += acc (plain RMW). Wo (K=512).
__global__ __launch_bounds__(256) void mfma_gemm_n64(
        const __hip_bfloat16* __restrict__ A, int lda,
        const __hip_bfloat16* __restrict__ B, int ldb,
        float* __restrict__ Cf, int ldc, int K, int nx) {
    __shared__ __hip_bfloat16 S[36864];   // 3 bufs x (A 16KB | B 8KB) = 72KB
    int tid = threadIdx.x;
    int lane = tid & 63, wave = tid >> 6;
    int L = blockIdx.x;
    int slots = (int)gridDim.x >> 3;
    int v = (L & 7) * slots + (L >> 3);
    int bx = v % nx, by = v / nx;
    int row0 = by * 128, col0 = bx * 64;
    f32x4 acc[2][4];
#pragma unroll
    for (int i = 0; i < 2; ++i)
#pragma unroll
        for (int j = 0; j < 4; ++j) acc[i][j] = (f32x4){0.f, 0.f, 0.f, 0.f};

    int fr = lane & 15, sl = lane >> 4;
    int T = K >> 6;

// Stage tile tt (A 128x64 = 4 loads/thr, B 64x64 = 2 loads/thr) into buf bb.
#define STAGEN(tt, bb)                                                        \
    do {                                                                      \
        int kk_ = (tt) * 64;                                                  \
        _Pragma("unroll")                                                     \
        for (int j = 0; j < 4; ++j) {                                         \
            int c = j * 256 + tid;                                            \
            int p = c >> 9, cp = c & 511;                                     \
            int r = cp >> 2, s = cp & 3;                                      \
            int kg = ((s ^ ((r >> 1) & 3)) << 3);                             \
            int cb = j * 256 + wave * 64;                                     \
            __builtin_amdgcn_global_load_lds(                                 \
                (const AS1 void*)(A + (size_t)(row0 + r) * lda + kk_ + p * 32 + kg), \
                (AS3 void*)(S + (bb) * 12288 + cb * 8), 16, 0, 0);            \
        }                                                                     \
        _Pragma("unroll")                                                     \
        for (int j = 0; j < 2; ++j) {                                         \
            int c = j * 256 + tid;                                            \
            int p = c >> 8, cp = c & 255;                                     \
            int r = cp >> 2, s = cp & 3;                                      \
            int kg = ((s ^ ((r >> 1) & 3)) << 3);                             \
            int cb = j * 256 + wave * 64;                                     \
            __builtin_amdgcn_global_load_lds(                                 \
                (const AS1 void*)(B + (size_t)(col0 + r) * ldb + kk_ + p * 32 + kg), \
                (AS3 void*)(S + (bb) * 12288 + 8192 + cb * 8), 16, 0, 0);     \
        }                                                                     \
    } while (0)

    STAGEN(0, 0);
    STAGEN(1, 1);
    for (int t = 0; t < T; ++t) {
        int tn = (t + 2 < T) ? t + 2 : 0;   // wrap keeps vmcnt uniform
        STAGEN(tn, (t + 2) % 3);
        asm volatile("s_waitcnt vmcnt(12)" ::: "memory");  // tile t's 6 done
        __builtin_amdgcn_s_barrier();
        asm volatile("" ::: "memory");
        const __hip_bfloat16* Ab = S + (t % 3) * 12288;
        const __hip_bfloat16* Bb = Ab + 8192;
#pragma unroll
        for (int ks = 0; ks < 2; ++ks) {
            short8 afr[2], bfr[4];
#pragma unroll
            for (int i = 0; i < 2; ++i)
                afr[i] = ld_sw(Ab + ks * 4096, wave * 32 + i * 16 + fr, sl);
#pragma unroll
            for (int j = 0; j < 4; ++j)
                bfr[j] = ld_sw(Bb + ks * 2048, j * 16 + fr, sl);
#pragma unroll
            for (int i = 0; i < 2; ++i)
#pragma unroll
                for (int j = 0; j < 4; ++j)
                    acc[i][j] = __builtin_amdgcn_mfma_f32_16x16x32_bf16(afr[i], bfr[j], acc[i][j], 0, 0, 0);
        }
        asm volatile("" ::: "memory");
        __builtin_amdgcn_s_barrier();   // readers done before next overwrite
        asm volatile("" ::: "memory");
    }
#undef STAGEN
    // drain dangling wrap-prefetch DMA before wave exit (LDS is freed then)
    asm volatile("s_waitcnt vmcnt(0)" ::: "memory");
    int rq = (lane >> 4) << 2;
#pragma unroll
    for (int i = 0; i < 2; ++i)
#pragma unroll
        for (int j = 0; j < 4; ++j)
#pragma unroll
            for (int gidx = 0; gidx < 4; ++gidx) {
                int r = row0 + wave * 32 + i * 16 + rq + gidx;
                int c = col0 + j * 16 + fr;
                Cf[(size_t)r * ldc + c] += acc[i][j][gidx];
            }
}

// ---------------------------------------------------------------------------
// FFN2 occupancy probe: identical 128x64 tile / wave tile / swizzle /
// staging pattern as mfma_gemm_n64, but 2 LDS buffers (48 KB -> THREE
// blocks/CU, 12 waves) with depth-1 prefetch (vmcnt(6)) and split-K x2
// (Ksp=2048, grid 1024 so 3 blocks actually co-reside). Tests the one
// untested axis: session data is monotone in blocks/CU (1=worst 80-82,
// 2=best 57-62); depth-1's measured cost ~5 us (r3) vs +50% TLP.
// Epilogue: fp32 unsafeAtomicAdd into out (proven r2-r3).
__global__ __launch_bounds__(256) void gemm_n64_sk(
        const __hip_bfloat16* __restrict__ A, int lda,
        const __hip_bfloat16* __restrict__ B, int ldb,
        float* __restrict__ Cf, int ldc, int Ksp, int nx) {
    __shared__ __hip_bfloat16 S[24576];   // 2 bufs x (A 16KB | B 8KB) = 48KB
    int tid = threadIdx.x;
    int lane = tid & 63, wave = tid >> 6;
    int L = blockIdx.x;
    int slots = (int)gridDim.x >> 3;
    int v = (L & 7) * slots + (L >> 3);
    int kq = v & 1;                   // 2-way split-K, fastest-varying
    int u = v >> 1;
    int bx = u % nx, by = u / nx;
    int row0 = by * 128, col0 = bx * 64;
    A += (size_t)kq * Ksp;
    B += (size_t)kq * Ksp;
    f32x4 acc[2][4];
#pragma unroll
    for (int i = 0; i < 2; ++i)
#pragma unroll
        for (int j = 0; j < 4; ++j) acc[i][j] = (f32x4){0.f, 0.f, 0.f, 0.f};

    int fr = lane & 15, sl = lane >> 4;
    int T = Ksp >> 6;

#define STAGES(tt, bb)                                                        \
    do {                                                                      \
        int kk_ = (tt) * 64;                                                  \
        _Pragma("unroll")                                                     \
        for (int j = 0; j < 4; ++j) {                                         \
            int c = j * 256 + tid;                                            \
            int p = c >> 9, cp = c & 511;                                     \
            int r = cp >> 2, s = cp & 3;                                      \
            int kg = ((s ^ ((r >> 1) & 3)) << 3);                             \
            int cb = j * 256 + wave * 64;                                     \
            __builtin_amdgcn_global_load_lds(                                 \
                (const AS1 void*)(A + (size_t)(row0 + r) * lda + kk_ + p * 32 + kg), \
                (AS3 void*)(S + (bb) * 12288 + cb * 8), 16, 0, 0);            \
        }                                                                     \
        _Pragma("unroll")                                                     \
        for (int j = 0; j < 2; ++j) {                                         \
            int c = j * 256 + tid;                                            \
            int p = c >> 8, cp = c & 255;                                     \
            int r = cp >> 2, s = cp & 3;                                      \
            int kg = ((s ^ ((r >> 1) & 3)) << 3);                             \
            int cb = j * 256 + wave * 64;                                     \
            __builtin_amdgcn_global_load_lds(                                 \
                (const AS1 void*)(B + (size_t)(col0 + r) * ldb + kk_ + p * 32 + kg), \
                (AS3 void*)(S + (bb) * 12288 + 8192 + cb * 8), 16, 0, 0);     \
        }                                                                     \
    } while (0)

    STAGES(0, 0);
    for (int t = 0; t < T; ++t) {
        int tn = (t + 1 < T) ? t + 1 : 0;   // wrap keeps vmcnt uniform
        STAGES(tn, (t + 1) & 1);
        asm volatile("s_waitcnt vmcnt(6)" ::: "memory");  // tile t's 6 done
        __builtin_amdgcn_s_barrier();
        asm volatile("" ::: "memory");
        const __hip_bfloat16* Ab = S + (t & 1) * 12288;
        const __hip_bfloat16* Bb = Ab + 8192;
#pragma unroll
        for (int ks = 0; ks < 2; ++ks) {
            short8 afr[2], bfr[4];
#pragma unroll
            for (int i = 0; i < 2; ++i)
                afr[i] = ld_sw(Ab + ks * 4096, wave * 32 + i * 16 + fr, sl);
#pragma unroll
            for (int j = 0; j < 4; ++j)
                bfr[j] = ld_sw(Bb + ks * 2048, j * 16 + fr, sl);
#pragma unroll
            for (int i = 0; i < 2; ++i)
#pragma unroll
                for (int j = 0; j < 4; ++j)
                    acc[i][j] = __builtin_amdgcn_mfma_f32_16x16x32_bf16(afr[i], bfr[j], acc[i][j], 0, 0, 0);
        }
        asm volatile("" ::: "memory");
        __builtin_amdgcn_s_barrier();   // readers done before next overwrite
        asm volatile("" ::: "memory");
    }
#undef STAGES
    // drain dangling wrap-prefetch DMA before exit
    asm volatile("s_waitcnt vmcnt(0)" ::: "memory");
    int rq = (lane >> 4) << 2;
#pragma unroll
    for (int i = 0; i < 2; ++i)
#pragma unroll
        for (int j = 0; j < 4; ++j)
#pragma unroll
            for (int gidx = 0; gidx < 4; ++gidx) {
                int r = row0 + wave * 32 + i * 16 + rq + gidx;
                int c = col0 + j * 16 + fr;
                unsafeAtomicAdd(&Cf[(size_t)r * ldc + c], acc[i][j][gidx]);
            }
}

// ---------------------------------------------------------------------------
// Shared swizzled ds_read for the 256x256 8-phase kernel ([r][64k] rows,
// 16B slot ^= row&7).
__device__ __forceinline__ short8 ld_frag(const __hip_bfloat16* base, int r, int slot) {
    return *(const short8*)(base + r * 64 + ((slot ^ (r & 7)) << 3));
}

// FFN1: 256x256 tile, BK=64, 8 waves (2m x 4n), 512 threads, 128 KiB LDS
// double-buffer. 8-phase schedule (T2 XOR-swizzle + T3/T4 counted vmcnt +
// T5 setprio). Works ONLY when A/B are L2-resident (xn_bf 8MB + w1T 4MB):
// vmcnt(6) covers ~3 phases ~= L2 latency, not L3/HBM (round-2 lesson).
// Epilogue: bias+relu -> LDS transpose -> bf16 stores.
__global__ __launch_bounds__(512, 2) void gemm256_8ph(
        const __hip_bfloat16* __restrict__ A, int lda,
        const __hip_bfloat16* __restrict__ B, int ldb,
        __hip_bfloat16* __restrict__ Cb, int ldc, int K,
        const float* __restrict__ bias, int nx) {
    __shared__ __hip_bfloat16 S[65536];      // A: [2buf][2half][128r][64k] 64KB | B same
    __hip_bfloat16* Asb = S;
    __hip_bfloat16* Bsb = S + 32768;
    int tid = threadIdx.x;
    int lane = tid & 63, wave = tid >> 6;
    int wm = wave >> 2, wn = wave & 3;
    int fr = lane & 15, l5 = lane >> 4;
    int L = blockIdx.x;
    int slots = (int)gridDim.x >> 3;
    int v = (L & 7) * slots + (L >> 3);
    int bx = v % nx, by = v / nx;
    int row0 = by * 256, col0 = bx * 256;
    int T = K >> 6;

    f32x4 acc[8][4];
#pragma unroll
    for (int i = 0; i < 8; ++i)
#pragma unroll
        for (int j = 0; j < 4; ++j) acc[i][j] = (f32x4){0.f, 0.f, 0.f, 0.f};

// Stage one half-tile (128 rows x 64 k = 16 KB): 2 global_load_lds / thread.
#define STAGE_A(tt, hh, bb)                                                   \
    do {                                                                      \
        _Pragma("unroll")                                                     \
        for (int j = 0; j < 2; ++j) {                                         \
            int c = j * 512 + tid;                                            \
            int r = c >> 3;                                                   \
            int sl = (c & 7) ^ (r & 7);                                       \
            int cb = j * 512 + wave * 64;                                     \
            int grow = row0 + ((r >> 6) << 7) + (hh) * 64 + (r & 63);         \
            __builtin_amdgcn_global_load_lds(                                 \
                (const AS1 void*)(A + (size_t)grow * lda + (tt) * 64 + sl * 8), \
                (AS3 void*)(Asb + (bb) * 16384 + (hh) * 8192 + cb * 8), 16, 0, 0); \
        }                                                                     \
    } while (0)
#define STAGE_B(tt, hh, bb)                                                   \
    do {                                                                      \
        _Pragma("unroll")                                                     \
        for (int j = 0; j < 2; ++j) {                                         \
            int c = j * 512 + tid;                                            \
            int r = c >> 3;                                                   \
            int sl = (c & 7) ^ (r & 7);                                       \
            int cb = j * 512 + wave * 64;                                     \
            int gcol = col0 + ((r >> 5) << 6) + (hh) * 32 + (r & 31);         \
            __builtin_amdgcn_global_load_lds(                                 \
                (const AS1 void*)(B + (size_t)gcol * ldb + (tt) * 64 + sl * 8), \
                (AS3 void*)(Bsb + (bb) * 16384 + (hh) * 8192 + cb * 8), 16, 0, 0); \
        }                                                                     \
    } while (0)

    // prologue: tile 0 into buf 0, issue order A0,B0,B1,A1 (8 loads)
    STAGE_A(0, 0, 0);
    STAGE_B(0, 0, 0);
    STAGE_B(0, 1, 0);
    STAGE_A(0, 1, 0);

    short8 a[4][2], b[2][2][2];
    for (int t = 0; t < T; ++t) {
        int buf = t & 1, nb = buf ^ 1;
        int tn = (t + 1 < T) ? t + 1 : 0;
        const __hip_bfloat16* Ab0 = Asb + buf * 16384;
        const __hip_bfloat16* Ab1 = Ab0 + 8192;
        const __hip_bfloat16* Bb0 = Bsb + buf * 16384;
        const __hip_bfloat16* Bb1 = Bb0 + 8192;

        // ---- phase 0: needs A-half0 + B-half0 -> m0-3 x n0-1
        STAGE_A(tn, 0, nb);
        asm volatile("s_waitcnt vmcnt(6)" ::: "memory");
        __builtin_amdgcn_s_barrier();
        asm volatile("" ::: "memory");
#pragma unroll
        for (int i = 0; i < 4; ++i)
#pragma unroll
            for (int ks = 0; ks < 2; ++ks)
                a[i][ks] = ld_frag(Ab0, wm * 64 + i * 16 + fr, ks * 4 + l5);
#pragma unroll
        for (int jj = 0; jj < 2; ++jj)
#pragma unroll
            for (int ks = 0; ks < 2; ++ks)
                b[0][jj][ks] = ld_frag(Bb0, wn * 32 + jj * 16 + fr, ks * 4 + l5);
        __builtin_amdgcn_s_setprio(1);
#pragma unroll
        for (int i = 0; i < 4; ++i)
#pragma unroll
            for (int jj = 0; jj < 2; ++jj)
#pragma unroll
                for (int ks = 0; ks < 2; ++ks)
                    acc[i][jj] = __builtin_amdgcn_mfma_f32_16x16x32_bf16(
                        a[i][ks], b[0][jj][ks], acc[i][jj], 0, 0, 0);
        __builtin_amdgcn_s_setprio(0);
        asm volatile("" ::: "memory");
        __builtin_amdgcn_s_barrier();
        asm volatile("" ::: "memory");

        // ---- phase 1: needs B-half1 -> m0-3 x n2-3
        STAGE_B(tn, 0, nb);
        asm volatile("s_waitcnt vmcnt(6)" ::: "memory");
        __builtin_amdgcn_s_barrier();
        asm volatile("" ::: "memory");
#pragma unroll
        for (int jj = 0; jj < 2; ++jj)
#pragma unroll
            for (int ks = 0; ks < 2; ++ks)
                b[1][jj][ks] = ld_frag(Bb1, wn * 32 + jj * 16 + fr, ks * 4 + l5);
        __builtin_amdgcn_s_setprio(1);
#pragma unroll
        for (int i = 0; i < 4; ++i)
#pragma unroll
            for (int jj = 0; jj < 2; ++jj)
#pragma unroll
                for (int ks = 0; ks < 2; ++ks)
                    acc[i][2 + jj] = __builtin_amdgcn_mfma_f32_16x16x32_bf16(
                        a[i][ks], b[1][jj][ks], acc[i][2 + jj], 0, 0, 0);
        __builtin_amdgcn_s_setprio(0);
        asm volatile("" ::: "memory");
        __builtin_amdgcn_s_barrier();
        asm volatile("" ::: "memory");

        // ---- phase 2: needs A-half1 -> m4-7 x n2-3
        STAGE_B(tn, 1, nb);
        asm volatile("s_waitcnt vmcnt(6)" ::: "memory");
        __builtin_amdgcn_s_barrier();
        asm volatile("" ::: "memory");
#pragma unroll
        for (int i = 0; i < 4; ++i)
#pragma unroll
            for (int ks = 0; ks < 2; ++ks)
                a[i][ks] = ld_frag(Ab1, wm * 64 + i * 16 + fr, ks * 4 + l5);
        __builtin_amdgcn_s_setprio(1);
#pragma unroll
        for (int i = 0; i < 4; ++i)
#pragma unroll
            for (int jj = 0; jj < 2; ++jj)
#pragma unroll
                for (int ks = 0; ks < 2; ++ks)
                    acc[4 + i][2 + jj] = __builtin_amdgcn_mfma_f32_16x16x32_bf16(
                        a[i][ks], b[1][jj][ks], acc[4 + i][2 + jj], 0, 0, 0);
        __builtin_amdgcn_s_setprio(0);
        asm volatile("" ::: "memory");
        __builtin_amdgcn_s_barrier();
        asm volatile("" ::: "memory");

        // ---- phase 3: all operands resident -> m4-7 x n0-1 (no vmcnt)
        STAGE_A(tn, 1, nb);
        asm volatile("" ::: "memory");
        __builtin_amdgcn_s_barrier();
        asm volatile("" ::: "memory");
        __builtin_amdgcn_s_setprio(1);
#pragma unroll
        for (int i = 0; i < 4; ++i)
#pragma unroll
            for (int jj = 0; jj < 2; ++jj)
#pragma unroll
                for (int ks = 0; ks < 2; ++ks)
                    acc[4 + i][jj] = __builtin_amdgcn_mfma_f32_16x16x32_bf16(
                        a[i][ks], b[0][jj][ks], acc[4 + i][jj], 0, 0, 0);
        __builtin_amdgcn_s_setprio(0);
        asm volatile("" ::: "memory");
        __builtin_amdgcn_s_barrier();
        asm volatile("" ::: "memory");
    }
#undef STAGE_A
#undef STAGE_B

    // ---- epilogue: bias+relu -> per-wave LDS transpose -> uint4 stores.
    __syncthreads();   // drains vmcnt(0) incl. wrap-prefetch before LDS reuse
    float bvv[4];
#pragma unroll
    for (int nj = 0; nj < 4; ++nj) bvv[nj] = bias[col0 + wn * 64 + nj * 16 + fr];
    unsigned short* Ew = (unsigned short*)S + wave * 1152;   // 16 x 72
    const __hip_bfloat16* Er = (const __hip_bfloat16*)Ew;
    int rq = l5 << 2;
    int rr = lane >> 2, cb2 = (lane & 3) * 16;
#pragma unroll
    for (int mi = 0; mi < 8; ++mi) {
#pragma unroll
        for (int nj = 0; nj < 4; ++nj)
#pragma unroll
            for (int gi = 0; gi < 4; ++gi) {
                float tv = acc[mi][nj][gi] + bvv[nj];
                Ew[(rq + gi) * 72 + nj * 16 + fr] = f2bfu(tv > 0.f ? tv : 0.f);
            }
        uint4 v0 = *(const uint4*)(Er + rr * 72 + cb2);
        uint4 v1 = *(const uint4*)(Er + rr * 72 + cb2 + 8);
        size_t rg = (size_t)(row0 + wm * 128 + mi * 16 + rr) * ldc
                    + col0 + wn * 64 + cb2;
        *(uint4*)(Cb + rg)     = v0;
        *(uint4*)(Cb + rg + 8) = v1;
    }
}

// ---------------------------------------------------------------------------
// MFMA flash attention, 32x32x16 MFMAs (2x FLOP per LDS operand read vs
// 16x16x32 -- the kernel is LDS-throughput-bound). One block = 128 Q rows of
// one (b,h); 4 waves x 32 rows, 256 threads. Single barrier per tile with
// K/V LDS ping-pong + register prefetch (r13 structure). No-max softmax
// (exp2; T^-0.5*log2e pre-folded into Wq); row-sums via B=ones MFMA.
// Layouts (m74/m101-verified C/D): col=lane&31, row=(reg&3)+8*(reg>>2)+
// 4*(lane>>5); A/B frag: m|n=lane&31, k=(lane>>5)*8+j.
__global__ __launch_bounds__(256) void attn_mfma(const __hip_bfloat16* __restrict__ qkvb,
        __hip_bfloat16* __restrict__ ob) {
    __shared__ __hip_bfloat16 KsS[2][64 * 72];  // K tiles [s][d], ping-pong
    __shared__ __hip_bfloat16 VtS[2][64 * 72];  // V^T tiles [d][s], ping-pong
    __shared__ __hip_bfloat16 PsS[4 * 32 * 72]; // P [wave][32 q][s]; Q overlays
    __hip_bfloat16* Qs = PsS;                   // Q staging [128 q][72]

    const unsigned short* q16 = (const unsigned short*)qkvb;
    int tid  = threadIdx.x;
    int lane = tid & 63, wave = tid >> 6;
    int l31 = lane & 31, l5 = lane >> 5;
    int blk = blockIdx.x;
    int qb  = 15 - (blk >> 5);                // global heavy-first
    int bh  = blk & 31;
    int b = bh >> 3, h = bh & 7;
    int base = qb * 128;
    size_t tokbase = (size_t)b * Tt;
    int qoff = h * 64, koff = 512 + h * 64, voff = 1024 + h * 64;

    {   // stage Q (already scaled): thread t -> row t>>1, 32 d
        int q = tid >> 1, dg = (tid & 1) * 32;
        const unsigned short* src = q16 + (tokbase + base + q) * 1536 + qoff + dg;
        uint4 a  = *(const uint4*)src;
        uint4 b4 = *(const uint4*)(src + 8);
        uint4 c4 = *(const uint4*)(src + 16);
        uint4 d4 = *(const uint4*)(src + 24);
        *(uint4*)(Qs + q * 72 + dg)      = a;
        *(uint4*)(Qs + q * 72 + dg + 8)  = b4;
        *(uint4*)(Qs + q * 72 + dg + 16) = c4;
        *(uint4*)(Qs + q * 72 + dg + 24) = d4;
    }
    __syncthreads();
    // Q A-frags: m=l31 (q row), k = kd*16 + l5*8 + j
    short8 aq[4];
#pragma unroll
    for (int kd = 0; kd < 4; ++kd)
        aq[kd] = *(const short8*)(Qs + (wave * 32 + l31) * 72 + kd * 16 + l5 * 8);

    short8 ones;
#pragma unroll
    for (int i = 0; i < 8; ++i) ones[i] = (short)0x3F80;   // bf16 1.0

    f32x16 acc[2], accL;
#pragma unroll
    for (int i = 0; i < 16; ++i) { acc[0][i] = 0.f; acc[1][i] = 0.f; accL[i] = 0.f; }
    __hip_bfloat16* Psw = PsS + wave * (32 * 72);
    unsigned short* Psw16 = (unsigned short*)Psw;

    // prefetch lane roles
    int s_k = tid >> 2, dg_k = (tid & 3) * 16;      // K: 2 uint4 per thread
    int sp = (tid & 31) * 2, dg8 = (tid >> 5) * 8;  // V: 2 uint4 per thread
    uint4 kr0, kr1, va, vb;
    {   // prologue: load tile 0
        const unsigned short* kp = q16 + (tokbase + s_k) * 1536 + koff + dg_k;
        kr0 = *(const uint4*)kp;
        kr1 = *(const uint4*)(kp + 8);
        const unsigned short* vp = q16 + (tokbase + sp) * 1536 + voff + dg8;
        va = *(const uint4*)vp;
        vb = *(const uint4*)(vp + 1536);
    }

    int tmax = 2 * qb + 1;
    for (int tile = 0; tile <= tmax; ++tile) {
        int buf = tile & 1;
        // ---- write prefetched K/V into this tile's buffer
        *(uint4*)(KsS[buf] + s_k * 72 + dg_k)     = kr0;
        *(uint4*)(KsS[buf] + s_k * 72 + dg_k + 8) = kr1;
        {
            unsigned a0[4] = {va.x, va.y, va.z, va.w};
            unsigned b0[4] = {vb.x, vb.y, vb.z, vb.w};
#pragma unroll
            for (int i = 0; i < 4; ++i) {
                unsigned p0 = (a0[i] & 0xffffu) | (b0[i] << 16);
                unsigned p1 = (a0[i] >> 16) | (b0[i] & 0xffff0000u);
                *(unsigned*)(VtS[buf] + (dg8 + 2 * i) * 72 + sp)     = p0;
                *(unsigned*)(VtS[buf] + (dg8 + 2 * i + 1) * 72 + sp) = p1;
            }
        }
        __syncthreads();                      // single barrier per tile
        if (tile < tmax) {                    // prefetch tile+1 under compute
            int s1 = (tile + 1) * 64;
            const unsigned short* kp = q16 + (tokbase + s1 + s_k) * 1536 + koff + dg_k;
            kr0 = *(const uint4*)kp;
            kr1 = *(const uint4*)(kp + 8);
            const unsigned short* vp = q16 + (tokbase + s1 + sp) * 1536 + voff + dg8;
            va = *(const uint4*)vp;
            vb = *(const uint4*)(vp + 1536);
        }
        if (tile == tmax && wave < 2) continue;   // fully masked for waves 0-1
        // ---- QK^T: S[32 q][64 s] per wave
        f32x16 Sc[2];
#pragma unroll
        for (int i = 0; i < 16; ++i) { Sc[0][i] = 0.f; Sc[1][i] = 0.f; }
#pragma unroll
        for (int st = 0; st < 2; ++st)
#pragma unroll
            for (int kd = 0; kd < 4; ++kd) {
                short8 bk = *(const short8*)(KsS[buf] + (st * 32 + l31) * 72 + kd * 16 + l5 * 8);
                Sc[st] = __builtin_amdgcn_mfma_f32_32x32x16_bf16(aq[kd], bk, Sc[st], 0, 0, 0);
            }
        if (tile >= 2 * qb) {                 // diagonal-straddling tiles
            int s0t = tile * 64;
            int qrb = base + wave * 32 + 4 * l5;
#pragma unroll
            for (int st = 0; st < 2; ++st) {
                int sg = s0t + st * 32 + l31;
#pragma unroll
                for (int reg = 0; reg < 16; ++reg) {
                    int qr = qrb + (reg & 3) + 8 * (reg >> 2);
                    if (sg > qr) Sc[st][reg] = -1e30f;
                }
            }
        }
        // ---- p = exp2(score) -> LDS (same-wave region, no barrier)
#pragma unroll
        for (int st = 0; st < 2; ++st)
#pragma unroll
            for (int reg = 0; reg < 16; ++reg) {
                int pr = (reg & 3) + 8 * (reg >> 2) + 4 * l5;
                Psw16[pr * 72 + st * 32 + l31] =
                    truncbf(__builtin_amdgcn_exp2f(Sc[st][reg]));
            }
        // ---- PV: O[32 q][64 d]; l via ones-MFMA
#pragma unroll
        for (int ks = 0; ks < 4; ++ks) {
            short8 ap = *(const short8*)(Psw + l31 * 72 + ks * 16 + l5 * 8);
            accL = __builtin_amdgcn_mfma_f32_32x32x16_bf16(ap, ones, accL, 0, 0, 0);
#pragma unroll
            for (int dt = 0; dt < 2; ++dt) {
                short8 bv = *(const short8*)(VtS[buf] + (dt * 32 + l31) * 72 + ks * 16 + l5 * 8);
                acc[dt] = __builtin_amdgcn_mfma_f32_32x32x16_bf16(ap, bv, acc[dt], 0, 0, 0);
            }
        }
    }
    // ---- epilogue: O[q][d] = acc/l -> o_bf [B*T][512]
#pragma unroll
    for (int reg = 0; reg < 16; ++reg) {
        float rl = 1.0f / accL[reg];
        int qr = base + wave * 32 + (reg & 3) + 8 * (reg >> 2) + 4 * l5;
#pragma unroll
        for (int dt = 0; dt < 2; ++dt)
            ob[(tokbase + qr) * 512 + h * 64 + dt * 32 + l31] =
                __float2bfloat16(acc[dt][reg] * rl);
    }
}

// ---------------------------------------------------------------------------
extern "C" void kernel_launch(void* const* d_in, const int* in_sizes, int n_in,
                              void* d_out, int out_size, void* d_ws, size_t ws_size,
                              hipStream_t stream) {
    const float* x   = (const float*)d_in[0];
    const float* Wq  = (const float*)d_in[1];
    const float* Wk  = (const float*)d_in[2];
    const float* Wv  = (const float*)d_in[3];
    const float* Wo  = (const float*)d_in[4];
    const float* bo  = (const float*)d_in[5];
    const float* W1  = (const float*)d_in[6];
    const float* b1  = (const float*)d_in[7];
    const float* W2  = (const float*)d_in[8];
    const float* b2  = (const float*)d_in[9];
    const float* g1  = (const float*)d_in[10];
    const float* be1 = (const float*)d_in[11];
    const float* g2  = (const float*)d_in[12];
    const float* be2 = (const float*)d_in[13];
    float* out = (float*)d_out;

    // Workspace layout (byte offsets, 16B aligned). Peak ~98 MB.
    char* ws = (char*)d_ws;
    __hip_bfloat16* bqT    = (__hip_bfloat16*)(ws);                  // [1536][512]
    __hip_bfloat16* woT    = (__hip_bfloat16*)(ws + 1572864);        // [512][512]
    __hip_bfloat16* w1T    = (__hip_bfloat16*)(ws + 2097152);        // [4096][512]
    __hip_bfloat16* w2T    = (__hip_bfloat16*)(ws + 6291456);        // [512][4096]
    float*          xn     = (float*)(ws + 10485760);                // [8192][512] fp32 (LN1+bo; Wo RMW -> x2)
    __hip_bfloat16* xn_bf  = (__hip_bfloat16*)(ws + 27262976);       // [8192][512] bf16
    __hip_bfloat16* qkv_bf = (__hip_bfloat16*)(ws + 35651584);       // [8192][1536] bf16
    __hip_bfloat16* o_bf   = (__hip_bfloat16*)(ws + 60817408);       // [8192][512] bf16
    __hip_bfloat16* h_bf   = (__hip_bfloat16*)(ws + 35651584);       // [8192][4096] overlay (qkv/o dead by FFN1)

    // 1. startup: LN1 (+bo fold) and all weight repacks, one dispatch
    startup_kernel<<<Mrows + 1280, 256, 0, stream>>>(
        x, g1, be1, bo, xn, xn_bf, Wq, Wk, Wv, Wo, W1, W2, bqT, woT, w1T, w2T);
    // 2. qkv = xn @ Wqkv  -> bf16   (grid 12x64; q columns pre-scaled)
    mfma_gemm<<<768, 256, 0, stream>>>(
        xn_bf, 512, bqT, 512, qkv_bf, 1536, 512, 12);
    // 3. causal attention (MFMA flash, 32x32x16, 1 barrier/tile) -> o_bf
    attn_mfma<<<Bsz * Hh * (Tt / 128), 256, 0, stream>>>(qkv_bf, o_bf);
    // 4. xn(=x2) += o @ Wo   (128x64 tiles, K=512, 3-buf vmcnt(12), grid 8x64)
    mfma_gemm_n64<<<512, 256, 0, stream>>>(
        o_bf, 512, woT, 512, xn, 512, 512, 8);
    // 5. LN2: out = LN(x2)+b2 (final residual base), xn_bf = LN(x2)
    ln_kernel<<<Mrows, 256, 0, stream>>>(xn, g2, be2, b2, out, xn_bf);
    // 6. h = relu(xn2 @ W1 + b1)  (256x256 8-phase T2/T4/T5 kernel, grid 16x32)
    gemm256_8ph<<<512, 512, 0, stream>>>(
        xn_bf, 512, w1T, 512, h_bf, HIDs, 512, b1, 16);
    // 7. out += h @ W2  (128x64 tiles, 2-buf 48KB -> 3 blk/CU, depth-1
    //    vmcnt(6), split-K x2, fp32 atomics; grid 8x64x2 = 1024)
    gemm_n64_sk<<<1024, 256, 0, stream>>>(
        h_bf, HIDs, w2T, HIDs, out, 512, 2048, 8);
}

// Round 11
// 293.294 us; speedup vs baseline: 1.0644x; 1.0644x over previous
//
#include <hip/hip_runtime.h>
#include <hip/hip_bf16.h>
#include <math.h>

// Problem constants (B,T,E)=(4,2048,512), H=8, D=64, HID=H*E=4096.
#define Bsz 4
#define Tt 2048
#define Ee 512
#define Hh 8
#define Dd 64
#define HIDs 4096
#define Mrows (Bsz * Tt)   // 8192 token rows

typedef __attribute__((ext_vector_type(8))) short short8;    // 8 bf16 (4 VGPRs)
typedef __attribute__((ext_vector_type(4))) float f32x4;     // 16x16 MFMA acc
typedef __attribute__((ext_vector_type(16))) float f32x16;   // 32x32 MFMA acc

#define AS1 __attribute__((address_space(1)))
#define AS3 __attribute__((address_space(3)))

__device__ __forceinline__ unsigned short f2bfu(float f) {   // RNE float->bf16 bits
    unsigned u = __float_as_uint(f);
    return (unsigned short)((u + 0x7fffu + ((u >> 16) & 1u)) >> 16);
}
__device__ __forceinline__ unsigned short truncbf(float f) { // truncating (P only)
    return (unsigned short)(__float_as_uint(f) >> 16);
}

// Swizzled ds_read for 64B-row LDS tiles ([row][4 x 16B slots], phys slot =
// logical slot ^ ((row>>1)&3): rows 0-7 cover all 8 (parity,slot) bank
// groups -> 2-way residual = free). Staging inverse-permutes the GLOBAL
// source k-offset (global_load_lds dest stays linear, rule #21).
__device__ __forceinline__ short8 ld_sw(const __hip_bfloat16* base, int R, int sl) {
    return *(const short8*)(base + R * 32 + (((sl) ^ ((R >> 1) & 3)) << 3));
}

// ---------------------------------------------------------------------------
// LN body (shared by startup + LN2 kernels).
__device__ __forceinline__ void ln_body(const float* __restrict__ x,
        const float* __restrict__ g, const float* __restrict__ b,
        const float* __restrict__ addb,
        float* __restrict__ out_f, __hip_bfloat16* __restrict__ out_bf,
        int row) {
    int tid = threadIdx.x;
    const float* xr = x + (size_t)row * Ee;
    float v0 = xr[tid];
    float v1 = xr[tid + 256];
    float s = v0 + v1;
    float sq = v0 * v0 + v1 * v1;
#pragma unroll
    for (int off = 32; off > 0; off >>= 1) {
        s  += __shfl_xor(s, off, 64);
        sq += __shfl_xor(sq, off, 64);
    }
    __shared__ float ls[4], lq[4];
    int wid = tid >> 6, lane = tid & 63;
    if (lane == 0) { ls[wid] = s; lq[wid] = sq; }
    __syncthreads();
    s  = ls[0] + ls[1] + ls[2] + ls[3];
    sq = lq[0] + lq[1] + lq[2] + lq[3];
    float mean = s * (1.0f / Ee);
    float var  = sq * (1.0f / Ee) - mean * mean;   // biased var, like jnp.var
    float rstd = rsqrtf(var + 1e-5f);
    float o0 = (v0 - mean) * rstd * g[tid]       + b[tid];
    float o1 = (v1 - mean) * rstd * g[tid + 256] + b[tid + 256];
    float* orow = out_f + (size_t)row * Ee;
    orow[tid]       = o0 + addb[tid];
    orow[tid + 256] = o1 + addb[tid + 256];
    __hip_bfloat16* brow = out_bf + (size_t)row * Ee;
    brow[tid]       = __float2bfloat16(o0);
    brow[tid + 256] = __float2bfloat16(o1);
}

__global__ __launch_bounds__(256) void ln_kernel(const float* __restrict__ x,
        const float* __restrict__ g, const float* __restrict__ b,
        const float* __restrict__ addb,
        float* __restrict__ out_f, __hip_bfloat16* __restrict__ out_bf) {
    ln_body(x, g, b, addb, out_f, out_bf, blockIdx.x);
}

// ---------------------------------------------------------------------------
// Startup: LN1 (blocks [0,8192)) + all weight repacks ([8192,9472)) fused.
__device__ __forceinline__ void tr_tile(const float* __restrict__ in,
        __hip_bfloat16* __restrict__ outp, int R, int C, int c0, int r0) {
    __shared__ float tile[64][65];
    int tc = threadIdx.x & 63, tg = threadIdx.x >> 6;
#pragma unroll
    for (int i = 0; i < 16; ++i) {
        int r = tg * 16 + i;
        tile[r][tc] = in[(size_t)(r0 + r) * C + c0 + tc];
    }
    __syncthreads();
#pragma unroll
    for (int i = 0; i < 16; ++i) {
        int cc = tg * 16 + i;
        outp[(size_t)(c0 + cc) * R + r0 + tc] = __float2bfloat16(tile[tc][cc]);
    }
}
__global__ __launch_bounds__(256) void startup_kernel(
        const float* __restrict__ x, const float* __restrict__ g1,
        const float* __restrict__ be1, const float* __restrict__ bo,
        float* __restrict__ xn, __hip_bfloat16* __restrict__ xn_bf,
        const float* __restrict__ Wq, const float* __restrict__ Wk,
        const float* __restrict__ Wv, const float* __restrict__ Wo,
        const float* __restrict__ W1, const float* __restrict__ W2,
        __hip_bfloat16* __restrict__ bqT, __hip_bfloat16* __restrict__ woT,
        __hip_bfloat16* __restrict__ w1T, __hip_bfloat16* __restrict__ w2T) {
    if (blockIdx.x < Mrows) {
        ln_body(x, g1, be1, bo, xn, xn_bf, blockIdx.x);
        return;
    }
    int blk = blockIdx.x - Mrows;
    if (blk < 192) {                 // qkv: p*64 + h*8 + et
        int p = blk >> 6, h = (blk >> 3) & 7, et = blk & 7;
        const float* W = (p == 0) ? Wq : ((p == 1) ? Wk : Wv);
        float sc = (p == 0) ? 0.022097086912079608f * 1.4426950408889634f : 1.0f;
        __shared__ float tile[64][65];
        int td = threadIdx.x & 63, tg = threadIdx.x >> 6;
#pragma unroll
        for (int i = 0; i < 16; ++i) {
            int e = tg * 16 + i;
            tile[e][td] = W[((size_t)h * Ee + et * 64 + e) * Dd + td] * sc;
        }
        __syncthreads();
#pragma unroll
        for (int i = 0; i < 16; ++i) {
            int d = tg * 16 + i;
            bqT[((size_t)(p * 512 + h * 64 + d)) * Ee + et * 64 + td] =
                __float2bfloat16(tile[td][d]);
        }
    } else if (blk < 256) {
        int t = blk - 192;           // 8x8
        tr_tile(Wo, woT, 512, 512, (t & 7) * 64, (t >> 3) * 64);
    } else if (blk < 768) {
        int t = blk - 256;           // 64x8
        tr_tile(W1, w1T, 512, HIDs, (t & 63) * 64, (t >> 6) * 64);
    } else {
        int t = blk - 768;           // 8x64
        tr_tile(W2, w2T, HIDs, 512, (t & 7) * 64, (t >> 3) * 64);
    }
}

// ---------------------------------------------------------------------------
// bf16 MFMA GEMM (QKV): 128x128 tile, BK=64, 2-buffer depth-1 prefetch with
// counted vmcnt(8) (tile t+1 staged before compute of t; never drain to 0
// in-loop) + bank-conflict swizzle. XCD swizzle. Epilogue: per-wave LDS
// transpose -> uint4 coalesced bf16 stores.
__global__ __launch_bounds__(256) void mfma_gemm(
        const __hip_bfloat16* __restrict__ A, int lda,
        const __hip_bfloat16* __restrict__ B, int ldb,
        __hip_bfloat16* __restrict__ Cb, int ldc, int K, int nx) {
    __shared__ __hip_bfloat16 S[32768];   // 2 bufs x (A 16KB | B 16KB) = 64KB
    int tid = threadIdx.x;
    int lane = tid & 63, wave = tid >> 6;
    int wm = wave >> 1, wn = wave & 1;
    int L = blockIdx.x;
    int slots = (int)gridDim.x >> 3;
    int v = (L & 7) * slots + (L >> 3);
    int bx = v % nx, by = v / nx;
    int row0 = by * 128, col0 = bx * 128;
    f32x4 acc[4][4];
#pragma unroll
    for (int i = 0; i < 4; ++i)
#pragma unroll
        for (int j = 0; j < 4; ++j) acc[i][j] = (f32x4){0.f, 0.f, 0.f, 0.f};

    int fr = lane & 15, sl = lane >> 4;
    int T = K >> 6;

// Stage tile tt (A 128x64 + B 128x64) into buffer bb. Dest linear; source
// k-offset inverse-swizzled to match ld_sw.
#define STAGEQ(tt, bb)                                                        \
    do {                                                                      \
        int kk_ = (tt) * 64;                                                  \
        _Pragma("unroll")                                                     \
        for (int j = 0; j < 4; ++j) {                                         \
            int c = j * 256 + tid;                                            \
            int p = c >> 9, cp = c & 511;                                     \
            int r = cp >> 2, s = cp & 3;                                      \
            int kg = ((s ^ ((r >> 1) & 3)) << 3);                             \
            int cb = j * 256 + wave * 64;                                     \
            int ko = kk_ + p * 32 + kg;                                       \
            __builtin_amdgcn_global_load_lds(                                 \
                (const AS1 void*)(A + (size_t)(row0 + r) * lda + ko),         \
                (AS3 void*)(S + (bb) * 16384 + cb * 8), 16, 0, 0);            \
            __builtin_amdgcn_global_load_lds(                                 \
                (const AS1 void*)(B + (size_t)(col0 + r) * ldb + ko),         \
                (AS3 void*)(S + (bb) * 16384 + 8192 + cb * 8), 16, 0, 0);     \
        }                                                                     \
    } while (0)

    STAGEQ(0, 0);
    for (int t = 0; t < T; ++t) {
        int tn = (t + 1 < T) ? t + 1 : 0;   // wrap keeps vmcnt uniform
        STAGEQ(tn, (t + 1) & 1);
        asm volatile("s_waitcnt vmcnt(8)" ::: "memory");  // tile t's loads done
        __builtin_amdgcn_s_barrier();
        asm volatile("" ::: "memory");
        const __hip_bfloat16* Ab = S + (t & 1) * 16384;
        const __hip_bfloat16* Bb = Ab + 8192;
#pragma unroll
        for (int ks = 0; ks < 2; ++ks) {
            short8 afr[4], bfr[4];
#pragma unroll
            for (int i = 0; i < 4; ++i) {
                afr[i] = ld_sw(Ab + ks * 4096, wm * 64 + i * 16 + fr, sl);
                bfr[i] = ld_sw(Bb + ks * 4096, wn * 64 + i * 16 + fr, sl);
            }
#pragma unroll
            for (int i = 0; i < 4; ++i)
#pragma unroll
                for (int j = 0; j < 4; ++j)
                    acc[i][j] = __builtin_amdgcn_mfma_f32_16x16x32_bf16(afr[i], bfr[j], acc[i][j], 0, 0, 0);
        }
        asm volatile("" ::: "memory");
        __builtin_amdgcn_s_barrier();   // readers done before next overwrite
        asm volatile("" ::: "memory");
    }
#undef STAGEQ
    // ---- epilogue: drain dangling wrap-prefetch DMA, then reuse LDS
    asm volatile("s_waitcnt vmcnt(0)" ::: "memory");
    __syncthreads();
    unsigned short* Ew = (unsigned short*)S + wave * 1152;   // 16 x 72
    const __hip_bfloat16* Er = (const __hip_bfloat16*)Ew;
    int rq = (lane >> 4) << 2;
    int rr = lane >> 2, cb2 = (lane & 3) * 16;
#pragma unroll
    for (int i = 0; i < 4; ++i) {
#pragma unroll
        for (int j = 0; j < 4; ++j)
#pragma unroll
            for (int gi = 0; gi < 4; ++gi)
                Ew[(rq + gi) * 72 + j * 16 + fr] = f2bfu(acc[i][j][gi]);
        uint4 v0 = *(const uint4*)(Er + rr * 72 + cb2);
        uint4 v1 = *(const uint4*)(Er + rr * 72 + cb2 + 8);
        size_t rg = (size_t)(row0 + wm * 64 + i * 16 + rr) * ldc + col0 + wn * 64 + cb2;
        *(uint4*)(Cb + rg)     = v0;
        *(uint4*)(Cb + rg + 8) = v1;
    }
}

// ---------------------------------------------------------------------------
// bf16 MFMA GEMM, 128x64 tile, full K. 4 waves x (32m x 64n). 3-buffer
// depth-2 prefetch with counted vmcnt(12) + bank-conflict swizzle.
// Epilogue: Cf[ci] += acc (plain RMW). Wo (K=512) and FFN2 (K=4096).
// SESSION-FINAL for FFN2: best of 8 measured configs (57.2 us; others:
// m64n128 59.6, 128^2-sk 62.2, 3blk/CU-sk 63.5, bk32 70.7, n256 80.0,
// 8ph-splitk 81.9). Probed axes: depth 1/2/3, BK 32/64, 5 tile geometries,
// split-K 1/2/4, occupancy 1/2/3 blk/CU (2 optimal, both directions worse),
// L3-traffic 0.71x/1x (falsified r7). Binding constraint: 2-phase
// counted-vmcnt structure's exposed-latency critical path; escape requires
// AITER-class interleaved-asm K-loop scheduling (guide m97/m233/s02).
__global__ __launch_bounds__(256) void mfma_gemm_n64(
        const __hip_bfloat16* __restrict__ A, int lda,
        const __hip_bfloat16* __restrict__ B, int ldb,
        float* __restrict__ Cf, int ldc, int K, int nx) {
    __shared__ __hip_bfloat16 S[36864];   // 3 bufs x (A 16KB | B 8KB) = 72KB
    int tid = threadIdx.x;
    int lane = tid & 63, wave = tid >> 6;
    int L = blockIdx.x;
    int slots = (int)gridDim.x >> 3;
    int v = (L & 7) * slots + (L >> 3);
    int bx = v % nx, by = v / nx;
    int row0 = by * 128, col0 = bx * 64;
    f32x4 acc[2][4];
#pragma unroll
    for (int i = 0; i < 2; ++i)
#pragma unroll
        for (int j = 0; j < 4; ++j) acc[i][j] = (f32x4){0.f, 0.f, 0.f, 0.f};

    int fr = lane & 15, sl = lane >> 4;
    int T = K >> 6;

// Stage tile tt (A 128x64 = 4 loads/thr, B 64x64 = 2 loads/thr) into buf bb.
#define STAGEN(tt, bb)                                                        \
    do {                                                                      \
        int kk_ = (tt) * 64;                                                  \
        _Pragma("unroll")                                                     \
        for (int j = 0; j < 4; ++j) {                                         \
            int c = j * 256 + tid;                                            \
            int p = c >> 9, cp = c & 511;                                     \
            int r = cp >> 2, s = cp & 3;                                      \
            int kg = ((s ^ ((r >> 1) & 3)) << 3);                             \
            int cb = j * 256 + wave * 64;                                     \
            __builtin_amdgcn_global_load_lds(                                 \
                (const AS1 void*)(A + (size_t)(row0 + r) * lda + kk_ + p * 32 + kg), \
                (AS3 void*)(S + (bb) * 12288 + cb * 8), 16, 0, 0);            \
        }                                                                     \
        _Pragma("unroll")                                                     \
        for (int j = 0; j < 2; ++j) {                                         \
            int c = j * 256 + tid;                                            \
            int p = c >> 8, cp = c & 255;                                     \
            int r = cp >> 2, s = cp & 3;                                      \
            int kg = ((s ^ ((r >> 1) & 3)) << 3);                             \
            int cb = j * 256 + wave * 64;                                     \
            __builtin_amdgcn_global_load_lds(                                 \
                (const AS1 void*)(B + (size_t)(col0 + r) * ldb + kk_ + p * 32 + kg), \
                (AS3 void*)(S + (bb) * 12288 + 8192 + cb * 8), 16, 0, 0);     \
        }                                                                     \
    } while (0)

    STAGEN(0, 0);
    STAGEN(1, 1);
    for (int t = 0; t < T; ++t) {
        int tn = (t + 2 < T) ? t + 2 : 0;   // wrap keeps vmcnt uniform
        STAGEN(tn, (t + 2) % 3);
        asm volatile("s_waitcnt vmcnt(12)" ::: "memory");  // tile t's 6 done
        __builtin_amdgcn_s_barrier();
        asm volatile("" ::: "memory");
        const __hip_bfloat16* Ab = S + (t % 3) * 12288;
        const __hip_bfloat16* Bb = Ab + 8192;
#pragma unroll
        for (int ks = 0; ks < 2; ++ks) {
            short8 afr[2], bfr[4];
#pragma unroll
            for (int i = 0; i < 2; ++i)
                afr[i] = ld_sw(Ab + ks * 4096, wave * 32 + i * 16 + fr, sl);
#pragma unroll
            for (int j = 0; j < 4; ++j)
                bfr[j] = ld_sw(Bb + ks * 2048, j * 16 + fr, sl);
#pragma unroll
            for (int i = 0; i < 2; ++i)
#pragma unroll
                for (int j = 0; j < 4; ++j)
                    acc[i][j] = __builtin_amdgcn_mfma_f32_16x16x32_bf16(afr[i], bfr[j], acc[i][j], 0, 0, 0);
        }
        asm volatile("" ::: "memory");
        __builtin_amdgcn_s_barrier();   // readers done before next overwrite
        asm volatile("" ::: "memory");
    }
#undef STAGEN
    // drain dangling wrap-prefetch DMA before wave exit (LDS is freed then)
    asm volatile("s_waitcnt vmcnt(0)" ::: "memory");
    int rq = (lane >> 4) << 2;
#pragma unroll
    for (int i = 0; i < 2; ++i)
#pragma unroll
        for (int j = 0; j < 4; ++j)
#pragma unroll
            for (int gidx = 0; gidx < 4; ++gidx) {
                int r = row0 + wave * 32 + i * 16 + rq + gidx;
                int c = col0 + j * 16 + fr;
                Cf[(size_t)r * ldc + c] += acc[i][j][gidx];
            }
}

// ---------------------------------------------------------------------------
// Shared swizzled ds_read for the 256x256 8-phase kernel ([r][64k] rows,
// 16B slot ^= row&7).
__device__ __forceinline__ short8 ld_frag(const __hip_bfloat16* base, int r, int slot) {
    return *(const short8*)(base + r * 64 + ((slot ^ (r & 7)) << 3));
}

// FFN1: 256x256 tile, BK=64, 8 waves (2m x 4n), 512 threads, 128 KiB LDS
// double-buffer. 8-phase schedule (T2 XOR-swizzle + T3/T4 counted vmcnt +
// T5 setprio). Works ONLY when A/B are L2-resident (xn_bf 8MB + w1T 4MB):
// vmcnt(6) covers ~3 phases ~= L2 latency, not L3/HBM (round-2 lesson).
// Epilogue: bias+relu -> LDS transpose -> bf16 stores. Session's principal
// structural win: 82 us (round 0) -> out of top-5 (~35-45 us), 2.3x.
__global__ __launch_bounds__(512, 2) void gemm256_8ph(
        const __hip_bfloat16* __restrict__ A, int lda,
        const __hip_bfloat16* __restrict__ B, int ldb,
        __hip_bfloat16* __restrict__ Cb, int ldc, int K,
        const float* __restrict__ bias, int nx) {
    __shared__ __hip_bfloat16 S[65536];      // A: [2buf][2half][128r][64k] 64KB | B same
    __hip_bfloat16* Asb = S;
    __hip_bfloat16* Bsb = S + 32768;
    int tid = threadIdx.x;
    int lane = tid & 63, wave = tid >> 6;
    int wm = wave >> 2, wn = wave & 3;
    int fr = lane & 15, l5 = lane >> 4;
    int L = blockIdx.x;
    int slots = (int)gridDim.x >> 3;
    int v = (L & 7) * slots + (L >> 3);
    int bx = v % nx, by = v / nx;
    int row0 = by * 256, col0 = bx * 256;
    int T = K >> 6;

    f32x4 acc[8][4];
#pragma unroll
    for (int i = 0; i < 8; ++i)
#pragma unroll
        for (int j = 0; j < 4; ++j) acc[i][j] = (f32x4){0.f, 0.f, 0.f, 0.f};

// Stage one half-tile (128 rows x 64 k = 16 KB): 2 global_load_lds / thread.
#define STAGE_A(tt, hh, bb)                                                   \
    do {                                                                      \
        _Pragma("unroll")                                                     \
        for (int j = 0; j < 2; ++j) {                                         \
            int c = j * 512 + tid;                                            \
            int r = c >> 3;                                                   \
            int sl = (c & 7) ^ (r & 7);                                       \
            int cb = j * 512 + wave * 64;                                     \
            int grow = row0 + ((r >> 6) << 7) + (hh) * 64 + (r & 63);         \
            __builtin_amdgcn_global_load_lds(                                 \
                (const AS1 void*)(A + (size_t)grow * lda + (tt) * 64 + sl * 8), \
                (AS3 void*)(Asb + (bb) * 16384 + (hh) * 8192 + cb * 8), 16, 0, 0); \
        }                                                                     \
    } while (0)
#define STAGE_B(tt, hh, bb)                                                   \
    do {                                                                      \
        _Pragma("unroll")                                                     \
        for (int j = 0; j < 2; ++j) {                                         \
            int c = j * 512 + tid;                                            \
            int r = c >> 3;                                                   \
            int sl = (c & 7) ^ (r & 7);                                       \
            int cb = j * 512 + wave * 64;                                     \
            int gcol = col0 + ((r >> 5) << 6) + (hh) * 32 + (r & 31);         \
            __builtin_amdgcn_global_load_lds(                                 \
                (const AS1 void*)(B + (size_t)gcol * ldb + (tt) * 64 + sl * 8), \
                (AS3 void*)(Bsb + (bb) * 16384 + (hh) * 8192 + cb * 8), 16, 0, 0); \
        }                                                                     \
    } while (0)

    // prologue: tile 0 into buf 0, issue order A0,B0,B1,A1 (8 loads)
    STAGE_A(0, 0, 0);
    STAGE_B(0, 0, 0);
    STAGE_B(0, 1, 0);
    STAGE_A(0, 1, 0);

    short8 a[4][2], b[2][2][2];
    for (int t = 0; t < T; ++t) {
        int buf = t & 1, nb = buf ^ 1;
        int tn = (t + 1 < T) ? t + 1 : 0;
        const __hip_bfloat16* Ab0 = Asb + buf * 16384;
        const __hip_bfloat16* Ab1 = Ab0 + 8192;
        const __hip_bfloat16* Bb0 = Bsb + buf * 16384;
        const __hip_bfloat16* Bb1 = Bb0 + 8192;

        // ---- phase 0: needs A-half0 + B-half0 -> m0-3 x n0-1
        STAGE_A(tn, 0, nb);
        asm volatile("s_waitcnt vmcnt(6)" ::: "memory");
        __builtin_amdgcn_s_barrier();
        asm volatile("" ::: "memory");
#pragma unroll
        for (int i = 0; i < 4; ++i)
#pragma unroll
            for (int ks = 0; ks < 2; ++ks)
                a[i][ks] = ld_frag(Ab0, wm * 64 + i * 16 + fr, ks * 4 + l5);
#pragma unroll
        for (int jj = 0; jj < 2; ++jj)
#pragma unroll
            for (int ks = 0; ks < 2; ++ks)
                b[0][jj][ks] = ld_frag(Bb0, wn * 32 + jj * 16 + fr, ks * 4 + l5);
        __builtin_amdgcn_s_setprio(1);
#pragma unroll
        for (int i = 0; i < 4; ++i)
#pragma unroll
            for (int jj = 0; jj < 2; ++jj)
#pragma unroll
                for (int ks = 0; ks < 2; ++ks)
                    acc[i][jj] = __builtin_amdgcn_mfma_f32_16x16x32_bf16(
                        a[i][ks], b[0][jj][ks], acc[i][jj], 0, 0, 0);
        __builtin_amdgcn_s_setprio(0);
        asm volatile("" ::: "memory");
        __builtin_amdgcn_s_barrier();
        asm volatile("" ::: "memory");

        // ---- phase 1: needs B-half1 -> m0-3 x n2-3
        STAGE_B(tn, 0, nb);
        asm volatile("s_waitcnt vmcnt(6)" ::: "memory");
        __builtin_amdgcn_s_barrier();
        asm volatile("" ::: "memory");
#pragma unroll
        for (int jj = 0; jj < 2; ++jj)
#pragma unroll
            for (int ks = 0; ks < 2; ++ks)
                b[1][jj][ks] = ld_frag(Bb1, wn * 32 + jj * 16 + fr, ks * 4 + l5);
        __builtin_amdgcn_s_setprio(1);
#pragma unroll
        for (int i = 0; i < 4; ++i)
#pragma unroll
            for (int jj = 0; jj < 2; ++jj)
#pragma unroll
                for (int ks = 0; ks < 2; ++ks)
                    acc[i][2 + jj] = __builtin_amdgcn_mfma_f32_16x16x32_bf16(
                        a[i][ks], b[1][jj][ks], acc[i][2 + jj], 0, 0, 0);
        __builtin_amdgcn_s_setprio(0);
        asm volatile("" ::: "memory");
        __builtin_amdgcn_s_barrier();
        asm volatile("" ::: "memory");

        // ---- phase 2: needs A-half1 -> m4-7 x n2-3
        STAGE_B(tn, 1, nb);
        asm volatile("s_waitcnt vmcnt(6)" ::: "memory");
        __builtin_amdgcn_s_barrier();
        asm volatile("" ::: "memory");
#pragma unroll
        for (int i = 0; i < 4; ++i)
#pragma unroll
            for (int ks = 0; ks < 2; ++ks)
                a[i][ks] = ld_frag(Ab1, wm * 64 + i * 16 + fr, ks * 4 + l5);
        __builtin_amdgcn_s_setprio(1);
#pragma unroll
        for (int i = 0; i < 4; ++i)
#pragma unroll
            for (int jj = 0; jj < 2; ++jj)
#pragma unroll
                for (int ks = 0; ks < 2; ++ks)
                    acc[4 + i][2 + jj] = __builtin_amdgcn_mfma_f32_16x16x32_bf16(
                        a[i][ks], b[1][jj][ks], acc[4 + i][2 + jj], 0, 0, 0);
        __builtin_amdgcn_s_setprio(0);
        asm volatile("" ::: "memory");
        __builtin_amdgcn_s_barrier();
        asm volatile("" ::: "memory");

        // ---- phase 3: all operands resident -> m4-7 x n0-1 (no vmcnt)
        STAGE_A(tn, 1, nb);
        asm volatile("" ::: "memory");
        __builtin_amdgcn_s_barrier();
        asm volatile("" ::: "memory");
        __builtin_amdgcn_s_setprio(1);
#pragma unroll
        for (int i = 0; i < 4; ++i)
#pragma unroll
            for (int jj = 0; jj < 2; ++jj)
#pragma unroll
                for (int ks = 0; ks < 2; ++ks)
                    acc[4 + i][jj] = __builtin_amdgcn_mfma_f32_16x16x32_bf16(
                        a[i][ks], b[0][jj][ks], acc[4 + i][jj], 0, 0, 0);
        __builtin_amdgcn_s_setprio(0);
        asm volatile("" ::: "memory");
        __builtin_amdgcn_s_barrier();
        asm volatile("" ::: "memory");
    }
#undef STAGE_A
#undef STAGE_B

    // ---- epilogue: bias+relu -> per-wave LDS transpose -> uint4 stores.
    __syncthreads();   // drains vmcnt(0) incl. wrap-prefetch before LDS reuse
    float bvv[4];
#pragma unroll
    for (int nj = 0; nj < 4; ++nj) bvv[nj] = bias[col0 + wn * 64 + nj * 16 + fr];
    unsigned short* Ew = (unsigned short*)S + wave * 1152;   // 16 x 72
    const __hip_bfloat16* Er = (const __hip_bfloat16*)Ew;
    int rq = l5 << 2;
    int rr = lane >> 2, cb2 = (lane & 3) * 16;
#pragma unroll
    for (int mi = 0; mi < 8; ++mi) {
#pragma unroll
        for (int nj = 0; nj < 4; ++nj)
#pragma unroll
            for (int gi = 0; gi < 4; ++gi) {
                float tv = acc[mi][nj][gi] + bvv[nj];
                Ew[(rq + gi) * 72 + nj * 16 + fr] = f2bfu(tv > 0.f ? tv : 0.f);
            }
        uint4 v0 = *(const uint4*)(Er + rr * 72 + cb2);
        uint4 v1 = *(const uint4*)(Er + rr * 72 + cb2 + 8);
        size_t rg = (size_t)(row0 + wm * 128 + mi * 16 + rr) * ldc
                    + col0 + wn * 64 + cb2;
        *(uint4*)(Cb + rg)     = v0;
        *(uint4*)(Cb + rg + 8) = v1;
    }
}

// ---------------------------------------------------------------------------
// MFMA flash attention, 32x32x16 MFMAs (2x FLOP per LDS operand read vs
// 16x16x32 -- the kernel is LDS-throughput-bound). One block = 128 Q rows of
// one (b,h); 4 waves x 32 rows, 256 threads. Single barrier per tile with
// K/V LDS ping-pong + register prefetch (r13 structure). No-max softmax
// (exp2; T^-0.5*log2e pre-folded into Wq); row-sums via B=ones MFMA.
// Layouts (m74/m101-verified C/D): col=lane&31, row=(reg&3)+8*(reg>>2)+
// 4*(lane>>5); A/B frag: m|n=lane&31, k=(lane>>5)*8+j.
__global__ __launch_bounds__(256) void attn_mfma(const __hip_bfloat16* __restrict__ qkvb,
        __hip_bfloat16* __restrict__ ob) {
    __shared__ __hip_bfloat16 KsS[2][64 * 72];  // K tiles [s][d], ping-pong
    __shared__ __hip_bfloat16 VtS[2][64 * 72];  // V^T tiles [d][s], ping-pong
    __shared__ __hip_bfloat16 PsS[4 * 32 * 72]; // P [wave][32 q][s]; Q overlays
    __hip_bfloat16* Qs = PsS;                   // Q staging [128 q][72]

    const unsigned short* q16 = (const unsigned short*)qkvb;
    int tid  = threadIdx.x;
    int lane = tid & 63, wave = tid >> 6;
    int l31 = lane & 31, l5 = lane >> 5;
    int blk = blockIdx.x;
    int qb  = 15 - (blk >> 5);                // global heavy-first
    int bh  = blk & 31;
    int b = bh >> 3, h = bh & 7;
    int base = qb * 128;
    size_t tokbase = (size_t)b * Tt;
    int qoff = h * 64, koff = 512 + h * 64, voff = 1024 + h * 64;

    {   // stage Q (already scaled): thread t -> row t>>1, 32 d
        int q = tid >> 1, dg = (tid & 1) * 32;
        const unsigned short* src = q16 + (tokbase + base + q) * 1536 + qoff + dg;
        uint4 a  = *(const uint4*)src;
        uint4 b4 = *(const uint4*)(src + 8);
        uint4 c4 = *(const uint4*)(src + 16);
        uint4 d4 = *(const uint4*)(src + 24);
        *(uint4*)(Qs + q * 72 + dg)      = a;
        *(uint4*)(Qs + q * 72 + dg + 8)  = b4;
        *(uint4*)(Qs + q * 72 + dg + 16) = c4;
        *(uint4*)(Qs + q * 72 + dg + 24) = d4;
    }
    __syncthreads();
    // Q A-frags: m=l31 (q row), k = kd*16 + l5*8 + j
    short8 aq[4];
#pragma unroll
    for (int kd = 0; kd < 4; ++kd)
        aq[kd] = *(const short8*)(Qs + (wave * 32 + l31) * 72 + kd * 16 + l5 * 8);

    short8 ones;
#pragma unroll
    for (int i = 0; i < 8; ++i) ones[i] = (short)0x3F80;   // bf16 1.0

    f32x16 acc[2], accL;
#pragma unroll
    for (int i = 0; i < 16; ++i) { acc[0][i] = 0.f; acc[1][i] = 0.f; accL[i] = 0.f; }
    __hip_bfloat16* Psw = PsS + wave * (32 * 72);
    unsigned short* Psw16 = (unsigned short*)Psw;

    // prefetch lane roles
    int s_k = tid >> 2, dg_k = (tid & 3) * 16;      // K: 2 uint4 per thread
    int sp = (tid & 31) * 2, dg8 = (tid >> 5) * 8;  // V: 2 uint4 per thread
    uint4 kr0, kr1, va, vb;
    {   // prologue: load tile 0
        const unsigned short* kp = q16 + (tokbase + s_k) * 1536 + koff + dg_k;
        kr0 = *(const uint4*)kp;
        kr1 = *(const uint4*)(kp + 8);
        const unsigned short* vp = q16 + (tokbase + sp) * 1536 + voff + dg8;
        va = *(const uint4*)vp;
        vb = *(const uint4*)(vp + 1536);
    }

    int tmax = 2 * qb + 1;
    for (int tile = 0; tile <= tmax; ++tile) {
        int buf = tile & 1;
        // ---- write prefetched K/V into this tile's buffer
        *(uint4*)(KsS[buf] + s_k * 72 + dg_k)     = kr0;
        *(uint4*)(KsS[buf] + s_k * 72 + dg_k + 8) = kr1;
        {
            unsigned a0[4] = {va.x, va.y, va.z, va.w};
            unsigned b0[4] = {vb.x, vb.y, vb.z, vb.w};
#pragma unroll
            for (int i = 0; i < 4; ++i) {
                unsigned p0 = (a0[i] & 0xffffu) | (b0[i] << 16);
                unsigned p1 = (a0[i] >> 16) | (b0[i] & 0xffff0000u);
                *(unsigned*)(VtS[buf] + (dg8 + 2 * i) * 72 + sp)     = p0;
                *(unsigned*)(VtS[buf] + (dg8 + 2 * i + 1) * 72 + sp) = p1;
            }
        }
        __syncthreads();                      // single barrier per tile
        if (tile < tmax) {                    // prefetch tile+1 under compute
            int s1 = (tile + 1) * 64;
            const unsigned short* kp = q16 + (tokbase + s1 + s_k) * 1536 + koff + dg_k;
            kr0 = *(const uint4*)kp;
            kr1 = *(const uint4*)(kp + 8);
            const unsigned short* vp = q16 + (tokbase + s1 + sp) * 1536 + voff + dg8;
            va = *(const uint4*)vp;
            vb = *(const uint4*)(vp + 1536);
        }
        if (tile == tmax && wave < 2) continue;   // fully masked for waves 0-1
        // ---- QK^T: S[32 q][64 s] per wave
        f32x16 Sc[2];
#pragma unroll
        for (int i = 0; i < 16; ++i) { Sc[0][i] = 0.f; Sc[1][i] = 0.f; }
#pragma unroll
        for (int st = 0; st < 2; ++st)
#pragma unroll
            for (int kd = 0; kd < 4; ++kd) {
                short8 bk = *(const short8*)(KsS[buf] + (st * 32 + l31) * 72 + kd * 16 + l5 * 8);
                Sc[st] = __builtin_amdgcn_mfma_f32_32x32x16_bf16(aq[kd], bk, Sc[st], 0, 0, 0);
            }
        if (tile >= 2 * qb) {                 // diagonal-straddling tiles
            int s0t = tile * 64;
            int qrb = base + wave * 32 + 4 * l5;
#pragma unroll
            for (int st = 0; st < 2; ++st) {
                int sg = s0t + st * 32 + l31;
#pragma unroll
                for (int reg = 0; reg < 16; ++reg) {
                    int qr = qrb + (reg & 3) + 8 * (reg >> 2);
                    if (sg > qr) Sc[st][reg] = -1e30f;
                }
            }
        }
        // ---- p = exp2(score) -> LDS (same-wave region, no barrier)
#pragma unroll
        for (int st = 0; st < 2; ++st)
#pragma unroll
            for (int reg = 0; reg < 16; ++reg) {
                int pr = (reg & 3) + 8 * (reg >> 2) + 4 * l5;
                Psw16[pr * 72 + st * 32 + l31] =
                    truncbf(__builtin_amdgcn_exp2f(Sc[st][reg]));
            }
        // ---- PV: O[32 q][64 d]; l via ones-MFMA
#pragma unroll
        for (int ks = 0; ks < 4; ++ks) {
            short8 ap = *(const short8*)(Psw + l31 * 72 + ks * 16 + l5 * 8);
            accL = __builtin_amdgcn_mfma_f32_32x32x16_bf16(ap, ones, accL, 0, 0, 0);
#pragma unroll
            for (int dt = 0; dt < 2; ++dt) {
                short8 bv = *(const short8*)(VtS[buf] + (dt * 32 + l31) * 72 + ks * 16 + l5 * 8);
                acc[dt] = __builtin_amdgcn_mfma_f32_32x32x16_bf16(ap, bv, acc[dt], 0, 0, 0);
            }
        }
    }
    // ---- epilogue: O[q][d] = acc/l -> o_bf [B*T][512]
#pragma unroll
    for (int reg = 0; reg < 16; ++reg) {
        float rl = 1.0f / accL[reg];
        int qr = base + wave * 32 + (reg & 3) + 8 * (reg >> 2) + 4 * l5;
#pragma unroll
        for (int dt = 0; dt < 2; ++dt)
            ob[(tokbase + qr) * 512 + h * 64 + dt * 32 + l31] =
                __float2bfloat16(acc[dt][reg] * rl);
    }
}

// ---------------------------------------------------------------------------
extern "C" void kernel_launch(void* const* d_in, const int* in_sizes, int n_in,
                              void* d_out, int out_size, void* d_ws, size_t ws_size,
                              hipStream_t stream) {
    const float* x   = (const float*)d_in[0];
    const float* Wq  = (const float*)d_in[1];
    const float* Wk  = (const float*)d_in[2];
    const float* Wv  = (const float*)d_in[3];
    const float* Wo  = (const float*)d_in[4];
    const float* bo  = (const float*)d_in[5];
    const float* W1  = (const float*)d_in[6];
    const float* b1  = (const float*)d_in[7];
    const float* W2  = (const float*)d_in[8];
    const float* b2  = (const float*)d_in[9];
    const float* g1  = (const float*)d_in[10];
    const float* be1 = (const float*)d_in[11];
    const float* g2  = (const float*)d_in[12];
    const float* be2 = (const float*)d_in[13];
    float* out = (float*)d_out;

    // Workspace layout (byte offsets, 16B aligned). Peak ~98 MB.
    char* ws = (char*)d_ws;
    __hip_bfloat16* bqT    = (__hip_bfloat16*)(ws);                  // [1536][512]
    __hip_bfloat16* woT    = (__hip_bfloat16*)(ws + 1572864);        // [512][512]
    __hip_bfloat16* w1T    = (__hip_bfloat16*)(ws + 2097152);        // [4096][512]
    __hip_bfloat16* w2T    = (__hip_bfloat16*)(ws + 6291456);        // [512][4096]
    float*          xn     = (float*)(ws + 10485760);                // [8192][512] fp32 (LN1+bo; Wo RMW -> x2)
    __hip_bfloat16* xn_bf  = (__hip_bfloat16*)(ws + 27262976);       // [8192][512] bf16
    __hip_bfloat16* qkv_bf = (__hip_bfloat16*)(ws + 35651584);       // [8192][1536] bf16
    __hip_bfloat16* o_bf   = (__hip_bfloat16*)(ws + 60817408);       // [8192][512] bf16
    __hip_bfloat16* h_bf   = (__hip_bfloat16*)(ws + 35651584);       // [8192][4096] overlay (qkv/o dead by FFN1)

    // 1. startup: LN1 (+bo fold) and all weight repacks, one dispatch
    startup_kernel<<<Mrows + 1280, 256, 0, stream>>>(
        x, g1, be1, bo, xn, xn_bf, Wq, Wk, Wv, Wo, W1, W2, bqT, woT, w1T, w2T);
    // 2. qkv = xn @ Wqkv  -> bf16   (grid 12x64; q columns pre-scaled)
    mfma_gemm<<<768, 256, 0, stream>>>(
        xn_bf, 512, bqT, 512, qkv_bf, 1536, 512, 12);
    // 3. causal attention (MFMA flash, 32x32x16, 1 barrier/tile) -> o_bf
    attn_mfma<<<Bsz * Hh * (Tt / 128), 256, 0, stream>>>(qkv_bf, o_bf);
    // 4. xn(=x2) += o @ Wo   (128x64 tiles, K=512, 3-buf vmcnt(12), grid 8x64)
    mfma_gemm_n64<<<512, 256, 0, stream>>>(
        o_bf, 512, woT, 512, xn, 512, 512, 8);
    // 5. LN2: out = LN(x2)+b2 (final residual base), xn_bf = LN(x2)
    ln_kernel<<<Mrows, 256, 0, stream>>>(xn, g2, be2, b2, out, xn_bf);
    // 6. h = relu(xn2 @ W1 + b1)  (256x256 8-phase T2/T4/T5 kernel, grid 16x32)
    gemm256_8ph<<<512, 512, 0, stream>>>(
        xn_bf, 512, w1T, 512, h_bf, HIDs, 512, b1, 16);
    // 7. out += h @ W2  (128x64 tiles, K=4096, 3-buf vmcnt(12), grid 8x64 --
    //    best measured FFN2 config across 8 variants this session)
    mfma_gemm_n64<<<512, 256, 0, stream>>>(
        h_bf, HIDs, w2T, HIDs, out, 512, HIDs, 8);
}